// Round 1
// baseline (755.903 us; speedup 1.0000x reference)
//
#include <hip/hip_runtime.h>

#define DEVI __device__ __forceinline__

#define B_    4
#define S_    2048
#define HID_  2048
#define H_    16
#define KV_   4
#define D_    128
#define NQKV_ 3072
#define SCALE_ 0.08838834764831845f
#define L2E_   1.44269504088896340736f

typedef __bf16 bf16x8 __attribute__((ext_vector_type(8)));
typedef float  f32x4  __attribute__((ext_vector_type(4)));
typedef unsigned short ushort_t;

DEVI unsigned short f2bu(float f) {            // f32 -> bf16 bits, RNE
  unsigned u = __float_as_uint(f);
  u += 0x7fffu + ((u >> 16) & 1u);
  return (unsigned short)(u >> 16);
}
DEVI float bu2f(unsigned short s) { return __uint_as_float(((unsigned)s) << 16); }

DEVI void storev(ushort_t* p, float v) { *p = f2bu(v); }
DEVI void storev(float* p, float v)    { *p = v; }

// async global->LDS, 16B/lane; LDS dest = wave-uniform base + lane*16 (m104)
DEVI void gl_lds16(const void* gptr, void* ldsptr) {
  __builtin_amdgcn_global_load_lds(
      (const __attribute__((address_space(1))) void*)gptr,
      (__attribute__((address_space(3))) void*)ldsptr, 16, 0, 0);
}

// ---------------- f32 -> bf16 elementwise (8/thread) ----------------
__global__ void k_cvt(const float* __restrict__ in, ushort_t* __restrict__ out, int n8) {
  int i = blockIdx.x * blockDim.x + threadIdx.x;
  if (i >= n8) return;
  const float4* p = (const float4*)in + (size_t)i * 2;
  float4 a = p[0], b = p[1];
  uint4 o;
  o.x = (unsigned)f2bu(a.x) | ((unsigned)f2bu(a.y) << 16);
  o.y = (unsigned)f2bu(a.z) | ((unsigned)f2bu(a.w) << 16);
  o.z = (unsigned)f2bu(b.x) | ((unsigned)f2bu(b.y) << 16);
  o.w = (unsigned)f2bu(b.z) | ((unsigned)f2bu(b.w) << 16);
  ((uint4*)out)[i] = o;
}

// ---------------- W (K x N, f32) -> Wt (N x K, bf16), LDS tile transpose ----
__global__ void k_transw(const float* __restrict__ in, ushort_t* __restrict__ out,
                         int K, int N) {
  __shared__ float tile[64][65];                       // +1 pad: conflict-free
  int k0 = blockIdx.x * 64, n0 = blockIdx.y * 64;
  int c = threadIdx.x & 63, r0 = threadIdx.x >> 6;
  #pragma unroll
  for (int i = 0; i < 16; ++i) {
    int r = r0 * 16 + i;
    tile[r][c] = in[(size_t)(k0 + r) * N + n0 + c];    // coalesced read
  }
  __syncthreads();
  #pragma unroll
  for (int i = 0; i < 16; ++i) {
    int r = r0 * 16 + i;
    out[(size_t)(n0 + r) * K + k0 + c] = f2bu(tile[c][r]);  // coalesced write
  }
}

// ---------------- bf16 GEMM: C(MxN) = A(MxK) * Bt(NxK)^T, m97 structure ----
template <typename OutT>
__global__ __launch_bounds__(256)
void k_gemm(const ushort_t* __restrict__ A, const ushort_t* __restrict__ Bt,
            OutT* __restrict__ C, int M, int N, int K) {
  __shared__ __align__(16) ushort_t As[128 * 64];      // [m][k] 16KB
  __shared__ __align__(16) ushort_t Bs[128 * 64];      // [n][k] 16KB
  const int tid = threadIdx.x;
  const int wave = tid >> 6, lane = tid & 63;
  const int wr = wave >> 1, wc = wave & 1;
  const int h4 = lane >> 4, c16 = lane & 15;
  const int m0 = blockIdx.x * 128, n0 = blockIdx.y * 128;

  const int srow  = wave * 8 + (lane >> 3);            // staging row (per pass +32)
  const int scolb = (lane & 7) * 16;                   // staging col bytes

  const ushort_t* Ap = A  + (size_t)m0 * K;
  const ushort_t* Bp = Bt + (size_t)n0 * K;

  f32x4 acc[4][4] = {};

  for (int kt = 0; kt < K; kt += 64) {
    __syncthreads();
    #pragma unroll
    for (int p = 0; p < 4; ++p) {
      int row = p * 32 + srow;
      gl_lds16((const char*)(Ap + (size_t)row * K + kt) + scolb,
               (char*)As + p * 4096 + wave * 1024);
      gl_lds16((const char*)(Bp + (size_t)row * K + kt) + scolb,
               (char*)Bs + p * 4096 + wave * 1024);
    }
    __syncthreads();
    #pragma unroll
    for (int kc = 0; kc < 2; ++kc) {
      bf16x8 af[4], bfr[4];
      #pragma unroll
      for (int m = 0; m < 4; ++m)
        af[m] = *(const bf16x8*)((const char*)As + (wr * 64 + m * 16 + c16) * 128 + kc * 64 + h4 * 16);
      #pragma unroll
      for (int n = 0; n < 4; ++n)
        bfr[n] = *(const bf16x8*)((const char*)Bs + (wc * 64 + n * 16 + c16) * 128 + kc * 64 + h4 * 16);
      #pragma unroll
      for (int m = 0; m < 4; ++m)
        #pragma unroll
        for (int n = 0; n < 4; ++n)
          acc[m][n] = __builtin_amdgcn_mfma_f32_16x16x32_bf16(af[m], bfr[n], acc[m][n], 0, 0, 0);
    }
  }
  // C/D layout: col = lane&15, row = (lane>>4)*4 + reg (m89/m91)
  #pragma unroll
  for (int m = 0; m < 4; ++m)
    #pragma unroll
    for (int n = 0; n < 4; ++n)
      #pragma unroll
      for (int r = 0; r < 4; ++r) {
        int grow = m0 + wr * 64 + m * 16 + h4 * 4 + r;
        int gcol = n0 + wc * 64 + n * 16 + c16;
        storev(&C[(size_t)grow * N + gcol], acc[m][n][r]);
      }
}

// ---------------- RMSNorm + RoPE + layout transform ----------------
// one wave per (b,s,row): rows 0..15 Q-heads, 16..19 K-heads, 20..23 V-heads
__global__ void k_normrope(const ushort_t* __restrict__ qkv,
                           const float* __restrict__ cosT, const float* __restrict__ sinT,
                           const float* __restrict__ qw, const float* __restrict__ kw,
                           ushort_t* __restrict__ Qr,   // (B,H,S,D)
                           ushort_t* __restrict__ Kr,   // (B,KV,S,D)
                           ushort_t* __restrict__ Vt) { // (B,KV,D,S)  pre-transposed
  int wid = blockIdx.x * 4 + (threadIdx.x >> 6);
  int lane = threadIdx.x & 63;
  int sub = wid % 24;
  int bs = wid / 24;
  int b = bs >> 11, s = bs & 2047;
  if (sub < 20) {
    bool isQ = sub < 16;
    int head = isQ ? sub : sub - 16;
    const ushort_t* rp = qkv + (size_t)bs * NQKV_ + (isQ ? head * 128 : 2048 + head * 128);
    float e0 = bu2f(rp[lane]);
    float e1 = bu2f(rp[lane + 64]);
    float ss2 = e0 * e0 + e1 * e1;
    #pragma unroll
    for (int off = 32; off; off >>= 1) ss2 += __shfl_xor(ss2, off);
    float rinv = rsqrtf(ss2 * (1.0f / 128.0f) + 1e-6f);
    const float* w = isQ ? qw : kw;
    float y0 = e0 * rinv * w[lane];
    float y1 = e1 * rinv * w[lane + 64];
    float c0 = cosT[s * 128 + lane],      sn0 = sinT[s * 128 + lane];
    float c1 = cosT[s * 128 + lane + 64], sn1 = sinT[s * 128 + lane + 64];
    float o0 = y0 * c0 - y1 * sn0;       // d < 64: q*cos - q[d+64]*sin
    float o1 = y1 * c1 + y0 * sn1;       // d >=64: q*cos + q[d-64]*sin
    if (isQ) { o0 *= SCALE_; o1 *= SCALE_; }   // fold score scale into Q
    ushort_t* op = isQ ? (Qr + ((size_t)(b * H_ + head) * S_ + s) * D_)
                       : (Kr + ((size_t)(b * KV_ + head) * S_ + s) * D_);
    op[lane]      = f2bu(o0);
    op[lane + 64] = f2bu(o1);
  } else {
    int vh = sub - 20;
    const ushort_t* rp = qkv + (size_t)bs * NQKV_ + 2560 + vh * 128;
    ushort_t* op = Vt + ((size_t)(b * KV_ + vh) * D_) * S_ + s;
    op[(size_t)lane * S_]        = rp[lane];       // scatter: V^T global layout
    op[(size_t)(lane + 64) * S_] = rp[lane + 64];
  }
}

// ---------------- flash attention (swapped QK^T, online softmax) -----------
// grid: x = S/64 q-tiles, y = b*16+h. 4 waves x 16 q-rows. KVBLK=64.
__global__ __launch_bounds__(256)
void k_attn(const ushort_t* __restrict__ Qr, const ushort_t* __restrict__ Kr,
            const ushort_t* __restrict__ Vt, ushort_t* __restrict__ AO) {
  __shared__ __align__(16) ushort_t Ks[64 * 128];     // [kv][d] swizzled, 16KB
  __shared__ __align__(16) ushort_t Vs[128 * 64];     // [d][kv] swizzled, 16KB
  __shared__ __align__(16) ushort_t Ps[4][16 * 64];   // per-wave P [q][kv] swz, 8KB
  const int bh = blockIdx.y;
  const int b = bh >> 4, h = bh & 15, kvh = h >> 2;
  const int q0 = blockIdx.x * 64;
  const int tid = threadIdx.x;
  const int wave = tid >> 6, lane = tid & 63;
  const int h4 = lane >> 4, c16 = lane & 15;

  // Q fragments (B-operand of scores^T): lane owns q-col = c16
  const ushort_t* qp = Qr + ((size_t)(b * H_ + h) * S_ + q0 + wave * 16 + c16) * D_;
  bf16x8 qf[4];
  #pragma unroll
  for (int kc = 0; kc < 4; ++kc)
    qf[kc] = *(const bf16x8*)(qp + kc * 32 + h4 * 8);

  const ushort_t* Kg = Kr + (size_t)(b * KV_ + kvh) * S_ * D_;
  const ushort_t* Vg = Vt + (size_t)(b * KV_ + kvh) * D_ * S_;

  float mrow = -1e30f, lsum = 0.0f;
  f32x4 Of[8] = {};
  ushort_t* pw = &Ps[wave][0];
  const int xq = (c16 & 7) << 4;

  for (int nt = 0; nt < S_ / 64; ++nt) {
    const int s0 = nt * 64;
    __syncthreads();
    #pragma unroll
    for (int p = 0; p < 4; ++p) {
      int off = p * 4096 + wave * 1024 + lane * 16;
      { // K tile: rows 256B; pre-swizzled global source, linear LDS dest
        int row = off >> 8, colb = off & 255;
        int sc = colb ^ ((row & 7) << 4);
        gl_lds16((const char*)(Kg + (size_t)(s0 + row) * D_) + sc,
                 (char*)Ks + p * 4096 + wave * 1024);
      }
      { // V^T tile: rows 128B
        int row = off >> 7, colb = off & 127;
        int sc = colb ^ ((row & 7) << 4);
        gl_lds16((const char*)(Vg + (size_t)row * S_ + s0) + sc,
                 (char*)Vs + p * 4096 + wave * 1024);
      }
    }
    __syncthreads();

    // scores^T (kv x q) = K * Q^T : both operands naturally row-major
    f32x4 st[4] = {};
    #pragma unroll
    for (int kvt = 0; kvt < 4; ++kvt) {
      const int krow = kvt * 16 + c16;
      const int xr = (krow & 7) << 4;
      #pragma unroll
      for (int kc = 0; kc < 4; ++kc) {
        bf16x8 kf = *(const bf16x8*)((const char*)Ks + krow * 256 + ((kc * 64 + h4 * 16) ^ xr));
        st[kvt] = __builtin_amdgcn_mfma_f32_16x16x32_bf16(kf, qf[kc], st[kvt], 0, 0, 0);
      }
    }

    // online softmax; lane owns q = c16, kv subset {kvt*16 + h4*4 + r}
    float tmax = -1e30f;
    #pragma unroll
    for (int kvt = 0; kvt < 4; ++kvt)
      #pragma unroll
      for (int r = 0; r < 4; ++r) tmax = fmaxf(tmax, st[kvt][r]);
    tmax = fmaxf(tmax, __shfl_xor(tmax, 16));
    tmax = fmaxf(tmax, __shfl_xor(tmax, 32));
    const float mnew = fmaxf(mrow, tmax);
    const float corr = exp2f((mrow - mnew) * L2E_);
    mrow = mnew;

    float psum = 0.0f;
    #pragma unroll
    for (int kvt = 0; kvt < 4; ++kvt)
      #pragma unroll
      for (int r = 0; r < 4; ++r) {
        float pv = exp2f((st[kvt][r] - mnew) * L2E_);
        psum += pv;
        int kvi = kvt * 16 + h4 * 4 + r;
        *(ushort_t*)((char*)pw + c16 * 128 + ((kvi * 2) ^ xq)) = f2bu(pv);
      }
    lsum = lsum * corr + psum;

    // rescale O: O-row q = h4*4+r, its corr lives at lane (group*16 + q)
    float cr[4];
    #pragma unroll
    for (int r = 0; r < 4; ++r) cr[r] = __shfl(corr, (lane & 48) + h4 * 4 + r);
    #pragma unroll
    for (int dt = 0; dt < 8; ++dt)
      #pragma unroll
      for (int r = 0; r < 4; ++r) Of[dt][r] *= cr[r];

    // PV: O(q,d) += P(q,kv) * V(kv,d);  A=P from Ps, B=V from Vs(=V^T)
    #pragma unroll
    for (int kvc = 0; kvc < 2; ++kvc) {
      bf16x8 pa = *(const bf16x8*)((const char*)pw + c16 * 128 + ((kvc * 64 + h4 * 16) ^ xq));
      #pragma unroll
      for (int dt = 0; dt < 8; ++dt) {
        const int vrow = dt * 16 + c16;
        bf16x8 vb = *(const bf16x8*)((const char*)Vs + vrow * 128 +
                                     ((kvc * 64 + h4 * 16) ^ ((vrow & 7) << 4)));
        Of[dt] = __builtin_amdgcn_mfma_f32_16x16x32_bf16(pa, vb, Of[dt], 0, 0, 0);
      }
    }
  }

  lsum += __shfl_xor(lsum, 16);
  lsum += __shfl_xor(lsum, 32);
  const float inv = 1.0f / lsum;
  float invr[4];
  #pragma unroll
  for (int r = 0; r < 4; ++r) invr[r] = __shfl(inv, (lane & 48) + h4 * 4 + r);

  #pragma unroll
  for (int dt = 0; dt < 8; ++dt)
    #pragma unroll
    for (int r = 0; r < 4; ++r) {
      const int s = q0 + wave * 16 + h4 * 4 + r;
      AO[((size_t)(b * S_ + s) * H_ + h) * D_ + dt * 16 + c16] = f2bu(Of[dt][r] * invr[r]);
    }
}

extern "C" void kernel_launch(void* const* d_in, const int* in_sizes, int n_in,
                              void* d_out, int out_size, void* d_ws, size_t ws_size,
                              hipStream_t stream) {
  const float* x    = (const float*)d_in[0];
  const float* cosT = (const float*)d_in[1];
  const float* sinT = (const float*)d_in[2];
  const float* Wq   = (const float*)d_in[3];
  const float* Wk   = (const float*)d_in[4];
  const float* Wv   = (const float*)d_in[5];
  const float* Wo   = (const float*)d_in[6];
  const float* qw   = (const float*)d_in[7];
  const float* kw   = (const float*)d_in[8];
  float* out = (float*)d_out;

  // workspace layout (121,634,816 B total, with aliasing)
  char* ws = (char*)d_ws;
  ushort_t* Xb    = (ushort_t*)(ws + 0);           // 33,554,432  X bf16 (8192x2048)
  ushort_t* QKVt  = (ushort_t*)(ws + 33554432);    // 50,331,648  QKV bf16 (8192x3072)
  ushort_t* Wtqkv = (ushort_t*)(ws + 83886080);    // 12,582,912  [Wq|Wk|Wv]^T (3072x2048)
  ushort_t* Wto   = (ushort_t*)(ws + 96468992);    //  8,388,608  Wo^T (2048x2048)
  ushort_t* Kr    = (ushort_t*)(ws + 104857600);   //  8,388,608  K (B,KV,S,D)
  ushort_t* Vt    = (ushort_t*)(ws + 113246208);   //  8,388,608  V^T (B,KV,D,S)
  ushort_t* Qr = Xb;     // alias: X dead after gemm1
  ushort_t* AO = QKVt;   // alias: QKV dead after normrope

  k_cvt<<<8192, 256, 0, stream>>>(x, Xb, 2097152);
  k_transw<<<dim3(32, 32), 256, 0, stream>>>(Wq, Wtqkv, 2048, 2048);
  k_transw<<<dim3(32, 8),  256, 0, stream>>>(Wk, Wtqkv + (size_t)2048 * 2048, 2048, 512);
  k_transw<<<dim3(32, 8),  256, 0, stream>>>(Wv, Wtqkv + (size_t)2560 * 2048, 2048, 512);
  k_transw<<<dim3(32, 32), 256, 0, stream>>>(Wo, Wto, 2048, 2048);
  k_gemm<ushort_t><<<dim3(64, 24), 256, 0, stream>>>(Xb, Wtqkv, QKVt, 8192, 3072, 2048);
  k_normrope<<<49152, 256, 0, stream>>>(QKVt, cosT, sinT, qw, kw, Qr, Kr, Vt);
  k_attn<<<dim3(32, 64), 256, 0, stream>>>(Qr, Kr, Vt, AO);
  k_gemm<float><<<dim3(64, 16), 256, 0, stream>>>(AO, Wto, out, 8192, 2048, 2048);
}

// Round 2
// 741.453 us; speedup vs baseline: 1.0195x; 1.0195x over previous
//
#include <hip/hip_runtime.h>

#define DEVI __device__ __forceinline__

#define B_    4
#define S_    2048
#define HID_  2048
#define H_    16
#define KV_   4
#define D_    128
#define NQKV_ 3072
#define SCALE_ 0.08838834764831845f
#define L2E_   1.44269504088896340736f

typedef __bf16 bf16x8 __attribute__((ext_vector_type(8)));
typedef float  f32x4  __attribute__((ext_vector_type(4)));
typedef unsigned short ushort_t;

DEVI unsigned short f2bu(float f) {            // f32 -> bf16 bits, RNE
  unsigned u = __float_as_uint(f);
  u += 0x7fffu + ((u >> 16) & 1u);
  return (unsigned short)(u >> 16);
}
DEVI float bu2f(unsigned short s) { return __uint_as_float(((unsigned)s) << 16); }
DEVI unsigned pk2(float a, float b) {
  return (unsigned)f2bu(a) | ((unsigned)f2bu(b) << 16);
}

DEVI void storev(ushort_t* p, float v) { *p = f2bu(v); }
DEVI void storev(float* p, float v)    { *p = v; }

// async global->LDS, 16B/lane; LDS dest = wave-uniform base + lane*16 (m104)
DEVI void gl_lds16(const void* gptr, void* ldsptr) {
  __builtin_amdgcn_global_load_lds(
      (const __attribute__((address_space(1))) void*)gptr,
      (__attribute__((address_space(3))) void*)ldsptr, 16, 0, 0);
}

// ---------------- f32 -> bf16 elementwise (8/thread) ----------------
__global__ void k_cvt(const float* __restrict__ in, ushort_t* __restrict__ out, int n8) {
  int i = blockIdx.x * blockDim.x + threadIdx.x;
  if (i >= n8) return;
  const float4* p = (const float4*)in + (size_t)i * 2;
  float4 a = p[0], b = p[1];
  uint4 o;
  o.x = pk2(a.x, a.y);
  o.y = pk2(a.z, a.w);
  o.z = pk2(b.x, b.y);
  o.w = pk2(b.z, b.w);
  ((uint4*)out)[i] = o;
}

// ---------------- W (K x N, f32) -> Wt (N x K, bf16), LDS tile transpose ----
__global__ void k_transw(const float* __restrict__ in, ushort_t* __restrict__ out,
                         int K, int N) {
  __shared__ float tile[64][65];                       // +1 pad: conflict-free
  int k0 = blockIdx.x * 64, n0 = blockIdx.y * 64;
  int c = threadIdx.x & 63, r0 = threadIdx.x >> 6;
  #pragma unroll
  for (int i = 0; i < 16; ++i) {
    int r = r0 * 16 + i;
    tile[r][c] = in[(size_t)(k0 + r) * N + n0 + c];    // coalesced read
  }
  __syncthreads();
  #pragma unroll
  for (int i = 0; i < 16; ++i) {
    int r = r0 * 16 + i;
    out[(size_t)(n0 + r) * K + k0 + c] = f2bu(tile[c][r]);  // coalesced write
  }
}

// ---------------- V slice of QKV -> V^T (B,KV,D,S), LDS transpose ----------
__global__ void k_vtrans(const ushort_t* __restrict__ qkv, ushort_t* __restrict__ Vt) {
  __shared__ ushort_t tile[64][65];
  int s0 = blockIdx.x * 64, d0 = blockIdx.y * 64;
  int bkv = blockIdx.z, b = bkv >> 2, vh = bkv & 3;
  int c = threadIdx.x & 63, r0 = (threadIdx.x >> 6) * 16;
  const ushort_t* src = qkv + (size_t)(b * S_ + s0) * NQKV_ + 2560 + vh * 128 + d0;
  #pragma unroll
  for (int i = 0; i < 16; ++i) {
    int r = r0 + i;
    tile[r][c] = src[(size_t)r * NQKV_ + c];           // coalesced 128B rows
  }
  __syncthreads();
  ushort_t* dst = Vt + ((size_t)(b * KV_ + vh) * D_ + d0) * S_ + s0;
  #pragma unroll
  for (int i = 0; i < 16; ++i) {
    int r = r0 + i;
    dst[(size_t)r * S_ + c] = tile[c][r];              // coalesced 128B rows
  }
}

// ---------------- bf16 GEMM: C(MxN) = A(MxK) * Bt(NxK)^T, m97 structure ----
template <typename OutT>
__global__ __launch_bounds__(256)
void k_gemm(const ushort_t* __restrict__ A, const ushort_t* __restrict__ Bt,
            OutT* __restrict__ C, int M, int N, int K) {
  __shared__ __align__(16) ushort_t As[128 * 64];      // [m][k] 16KB
  __shared__ __align__(16) ushort_t Bs[128 * 64];      // [n][k] 16KB
  const int tid = threadIdx.x;
  const int wave = tid >> 6, lane = tid & 63;
  const int wr = wave >> 1, wc = wave & 1;
  const int h4 = lane >> 4, c16 = lane & 15;
  const int m0 = blockIdx.x * 128, n0 = blockIdx.y * 128;

  const int srow  = wave * 8 + (lane >> 3);
  const int scolb = (lane & 7) * 16;

  const ushort_t* Ap = A  + (size_t)m0 * K;
  const ushort_t* Bp = Bt + (size_t)n0 * K;

  f32x4 acc[4][4] = {};

  for (int kt = 0; kt < K; kt += 64) {
    __syncthreads();
    #pragma unroll
    for (int p = 0; p < 4; ++p) {
      int row = p * 32 + srow;
      gl_lds16((const char*)(Ap + (size_t)row * K + kt) + scolb,
               (char*)As + p * 4096 + wave * 1024);
      gl_lds16((const char*)(Bp + (size_t)row * K + kt) + scolb,
               (char*)Bs + p * 4096 + wave * 1024);
    }
    __syncthreads();
    #pragma unroll
    for (int kc = 0; kc < 2; ++kc) {
      bf16x8 af[4], bfr[4];
      #pragma unroll
      for (int m = 0; m < 4; ++m)
        af[m] = *(const bf16x8*)((const char*)As + (wr * 64 + m * 16 + c16) * 128 + kc * 64 + h4 * 16);
      #pragma unroll
      for (int n = 0; n < 4; ++n)
        bfr[n] = *(const bf16x8*)((const char*)Bs + (wc * 64 + n * 16 + c16) * 128 + kc * 64 + h4 * 16);
      #pragma unroll
      for (int m = 0; m < 4; ++m)
        #pragma unroll
        for (int n = 0; n < 4; ++n)
          acc[m][n] = __builtin_amdgcn_mfma_f32_16x16x32_bf16(af[m], bfr[n], acc[m][n], 0, 0, 0);
    }
  }
  #pragma unroll
  for (int m = 0; m < 4; ++m)
    #pragma unroll
    for (int n = 0; n < 4; ++n)
      #pragma unroll
      for (int r = 0; r < 4; ++r) {
        int grow = m0 + wr * 64 + m * 16 + h4 * 4 + r;
        int gcol = n0 + wc * 64 + n * 16 + c16;
        storev(&C[(size_t)grow * N + gcol], acc[m][n][r]);
      }
}

// ---------------- RMSNorm + RoPE (Q,K only) ----------------
// one wave per (b,s,row): rows 0..15 Q-heads, 16..19 K-heads
__global__ void k_normrope(const ushort_t* __restrict__ qkv,
                           const float* __restrict__ cosT, const float* __restrict__ sinT,
                           const float* __restrict__ qw, const float* __restrict__ kw,
                           ushort_t* __restrict__ Qr,   // (B,H,S,D)
                           ushort_t* __restrict__ Kr) { // (B,KV,S,D)
  int wid = blockIdx.x * 4 + (threadIdx.x >> 6);
  int lane = threadIdx.x & 63;
  int sub = wid % 20;
  int bs = wid / 20;
  int b = bs >> 11, s = bs & 2047;
  bool isQ = sub < 16;
  int head = isQ ? sub : sub - 16;
  const ushort_t* rp = qkv + (size_t)bs * NQKV_ + (isQ ? head * 128 : 2048 + head * 128);
  float e0 = bu2f(rp[lane]);
  float e1 = bu2f(rp[lane + 64]);
  float ss2 = e0 * e0 + e1 * e1;
  #pragma unroll
  for (int off = 32; off; off >>= 1) ss2 += __shfl_xor(ss2, off);
  float rinv = rsqrtf(ss2 * (1.0f / 128.0f) + 1e-6f);
  const float* w = isQ ? qw : kw;
  float y0 = e0 * rinv * w[lane];
  float y1 = e1 * rinv * w[lane + 64];
  float c0 = cosT[s * 128 + lane],      sn0 = sinT[s * 128 + lane];
  float c1 = cosT[s * 128 + lane + 64], sn1 = sinT[s * 128 + lane + 64];
  float o0 = y0 * c0 - y1 * sn0;
  float o1 = y1 * c1 + y0 * sn1;
  if (isQ) { o0 *= SCALE_; o1 *= SCALE_; }
  ushort_t* op = isQ ? (Qr + ((size_t)(b * H_ + head) * S_ + s) * D_)
                     : (Kr + ((size_t)(b * KV_ + head) * S_ + s) * D_);
  op[lane]      = f2bu(o0);
  op[lane + 64] = f2bu(o1);
}

// ---------------- flash attention v2 ---------------------------------------
// swapped QK^T AND swapped PV (O^T = V^T P^T): q = lane column end-to-end.
// P stays in registers (shfl redistribution, no LDS). K/V double-buffered,
// 2-phase pipeline: STAGE(next) -> compute(cur) -> vmcnt(0) -> s_barrier.
__global__ __launch_bounds__(256)
void k_attn(const ushort_t* __restrict__ Qr, const ushort_t* __restrict__ Kr,
            const ushort_t* __restrict__ Vt, ushort_t* __restrict__ AO) {
  __shared__ __align__(16) ushort_t Ks[2][64 * 128];  // [kv][d] swizzled, 2x16KB
  __shared__ __align__(16) ushort_t Vs[2][64 * 128];  // [d][kv] swizzled, 2x16KB
  const int bh = blockIdx.y;
  const int b = bh >> 4, h = bh & 15, kvh = h >> 2;
  const int q0 = blockIdx.x * 64;
  const int tid = threadIdx.x;
  const int wave = tid >> 6, lane = tid & 63;
  const int h4 = lane >> 4, c16 = lane & 15;

  // Q fragments (B-operand of scores^T): lane owns q-col = c16
  const ushort_t* qp = Qr + ((size_t)(b * H_ + h) * S_ + q0 + wave * 16 + c16) * D_;
  bf16x8 qf[4];
  #pragma unroll
  for (int kc = 0; kc < 4; ++kc)
    qf[kc] = *(const bf16x8*)(qp + kc * 32 + h4 * 8);

  const ushort_t* Kg = Kr + (size_t)(b * KV_ + kvh) * S_ * D_;
  const ushort_t* Vg = Vt + (size_t)(b * KV_ + kvh) * D_ * S_;

  const int soff = wave * 1024 + lane * 16;

  float mrow = -1e30f, lsum = 0.0f;
  f32x4 Of[8] = {};

  // --- staging: 8 x gl_lds16 per wave; pre-swizzled global src, linear dest
#define STAGE(bufi, s0)                                                        \
  {                                                                            \
    _Pragma("unroll")                                                          \
    for (int p = 0; p < 4; ++p) {                                              \
      int off = p * 4096 + soff;                                               \
      int krow = off >> 8, kcolb = off & 255;                                  \
      int ksc = kcolb ^ ((krow & 7) << 4);                                     \
      gl_lds16((const char*)(Kg + (size_t)((s0) + krow) * D_) + ksc,           \
               (char*)Ks[bufi] + p * 4096 + wave * 1024);                      \
      int vrow = off >> 7, vcolb = off & 127;                                  \
      int vsc = vcolb ^ ((vrow & 7) << 4);                                     \
      gl_lds16((const char*)(Vg + (size_t)vrow * S_ + (s0)) + vsc,             \
               (char*)Vs[bufi] + p * 4096 + wave * 1024);                      \
    }                                                                          \
  }

  STAGE(0, 0);
  asm volatile("s_waitcnt vmcnt(0)" ::: "memory");
  __builtin_amdgcn_s_barrier();

  const int srcA = (2 * (h4 & 1)) * 16 + c16;   // shfl source lanes for P^T
  const int srcB = srcA + 16;
  const bool hiKvt = (h4 >> 1) != 0;

  for (int nt = 0; nt < S_ / 64; ++nt) {
    const int cur = nt & 1;
    if (nt + 1 < S_ / 64) STAGE(cur ^ 1, (nt + 1) * 64);

    // ---- scores^T (kv x q) = K * Q^T
    f32x4 st[4] = {};
    #pragma unroll
    for (int kvt = 0; kvt < 4; ++kvt) {
      const int krow = kvt * 16 + c16;
      const int xr = (krow & 7) << 4;
      #pragma unroll
      for (int kc = 0; kc < 4; ++kc) {
        bf16x8 kf = *(const bf16x8*)((const char*)Ks[cur] + krow * 256 +
                                     ((kc * 64 + h4 * 16) ^ xr));
        st[kvt] = __builtin_amdgcn_mfma_f32_16x16x32_bf16(kf, qf[kc], st[kvt], 0, 0, 0);
      }
    }

    // ---- online softmax; lane owns q = c16, kv subset {kvt*16 + h4*4 + r}
    float tmax = -1e30f;
    #pragma unroll
    for (int kvt = 0; kvt < 4; ++kvt)
      #pragma unroll
      for (int r = 0; r < 4; ++r) tmax = fmaxf(tmax, st[kvt][r]);
    tmax = fmaxf(tmax, __shfl_xor(tmax, 16));
    tmax = fmaxf(tmax, __shfl_xor(tmax, 32));
    const float mnew = fmaxf(mrow, tmax);
    const float corr = exp2f((mrow - mnew) * L2E_);
    mrow = mnew;

    float psum = 0.0f;
    unsigned pu[4][2];
    #pragma unroll
    for (int kvt = 0; kvt < 4; ++kvt) {
      float p0 = exp2f((st[kvt][0] - mnew) * L2E_);
      float p1 = exp2f((st[kvt][1] - mnew) * L2E_);
      float p2 = exp2f((st[kvt][2] - mnew) * L2E_);
      float p3 = exp2f((st[kvt][3] - mnew) * L2E_);
      psum += (p0 + p1) + (p2 + p3);
      pu[kvt][0] = pk2(p0, p1);
      pu[kvt][1] = pk2(p2, p3);
    }
    lsum = lsum * corr + psum;

    // ---- rescale O^T (all entries have q = c16): no shuffles needed
    #pragma unroll
    for (int dt = 0; dt < 8; ++dt)
      #pragma unroll
      for (int r = 0; r < 4; ++r) Of[dt][r] *= corr;

    // ---- PV: O^T(d,q) += V^T(d,kv) * P^T(kv,q)
    // B-frag (P^T): lane needs kv = kvc*32 + h4*8 .. +8 for q=c16, gathered
    // from lanes (2*(h4&1)[+1])*16+c16, acc kvt' = kvc*2 + (h4>>1).
    #pragma unroll
    for (int kvc = 0; kvc < 2; ++kvc) {
      unsigned w0a = __shfl(pu[kvc * 2][0], srcA), w0b = __shfl(pu[kvc * 2 + 1][0], srcA);
      unsigned w1a = __shfl(pu[kvc * 2][1], srcA), w1b = __shfl(pu[kvc * 2 + 1][1], srcA);
      unsigned w2a = __shfl(pu[kvc * 2][0], srcB), w2b = __shfl(pu[kvc * 2 + 1][0], srcB);
      unsigned w3a = __shfl(pu[kvc * 2][1], srcB), w3b = __shfl(pu[kvc * 2 + 1][1], srcB);
      uint4 pw;
      pw.x = hiKvt ? w0b : w0a;
      pw.y = hiKvt ? w1b : w1a;
      pw.z = hiKvt ? w2b : w2a;
      pw.w = hiKvt ? w3b : w3a;
      bf16x8 pb = __builtin_bit_cast(bf16x8, pw);
      #pragma unroll
      for (int dt = 0; dt < 8; ++dt) {
        const int vrow = dt * 16 + c16;
        bf16x8 vb = *(const bf16x8*)((const char*)Vs[cur] + vrow * 128 +
                                     ((kvc * 64 + h4 * 16) ^ ((vrow & 7) << 4)));
        Of[dt] = __builtin_amdgcn_mfma_f32_16x16x32_bf16(vb, pb, Of[dt], 0, 0, 0);
      }
    }

    asm volatile("s_waitcnt vmcnt(0)" ::: "memory");
    __builtin_amdgcn_s_barrier();
  }
#undef STAGE

  lsum += __shfl_xor(lsum, 16);
  lsum += __shfl_xor(lsum, 32);
  const float inv = 1.0f / lsum;

  // O^T: lane holds q=c16 col, rows d = dt*16 + h4*4 + r -> pack r-pairs
  const int s = q0 + wave * 16 + c16;
  ushort_t* aop = AO + ((size_t)(b * S_ + s) * H_ + h) * D_;
  #pragma unroll
  for (int dt = 0; dt < 8; ++dt) {
    const int d0 = dt * 16 + h4 * 4;
    *(unsigned*)(aop + d0)     = pk2(Of[dt][0] * inv, Of[dt][1] * inv);
    *(unsigned*)(aop + d0 + 2) = pk2(Of[dt][2] * inv, Of[dt][3] * inv);
  }
}

extern "C" void kernel_launch(void* const* d_in, const int* in_sizes, int n_in,
                              void* d_out, int out_size, void* d_ws, size_t ws_size,
                              hipStream_t stream) {
  const float* x    = (const float*)d_in[0];
  const float* cosT = (const float*)d_in[1];
  const float* sinT = (const float*)d_in[2];
  const float* Wq   = (const float*)d_in[3];
  const float* Wk   = (const float*)d_in[4];
  const float* Wv   = (const float*)d_in[5];
  const float* Wo   = (const float*)d_in[6];
  const float* qw   = (const float*)d_in[7];
  const float* kw   = (const float*)d_in[8];
  float* out = (float*)d_out;

  // workspace layout (121,634,816 B total, with aliasing)
  char* ws = (char*)d_ws;
  ushort_t* Xb    = (ushort_t*)(ws + 0);           // 33,554,432  X bf16 (8192x2048)
  ushort_t* QKVt  = (ushort_t*)(ws + 33554432);    // 50,331,648  QKV bf16 (8192x3072)
  ushort_t* Wtqkv = (ushort_t*)(ws + 83886080);    // 12,582,912  [Wq|Wk|Wv]^T (3072x2048)
  ushort_t* Wto   = (ushort_t*)(ws + 96468992);    //  8,388,608  Wo^T (2048x2048)
  ushort_t* Kr    = (ushort_t*)(ws + 104857600);   //  8,388,608  K (B,KV,S,D)
  ushort_t* Vt    = (ushort_t*)(ws + 113246208);   //  8,388,608  V^T (B,KV,D,S)
  ushort_t* Qr = Xb;     // alias: X dead after gemm1
  ushort_t* AO = QKVt;   // alias: QKV dead after normrope+vtrans

  k_cvt<<<8192, 256, 0, stream>>>(x, Xb, 2097152);
  k_transw<<<dim3(32, 32), 256, 0, stream>>>(Wq, Wtqkv, 2048, 2048);
  k_transw<<<dim3(32, 8),  256, 0, stream>>>(Wk, Wtqkv + (size_t)2048 * 2048, 2048, 512);
  k_transw<<<dim3(32, 8),  256, 0, stream>>>(Wv, Wtqkv + (size_t)2560 * 2048, 2048, 512);
  k_transw<<<dim3(32, 32), 256, 0, stream>>>(Wo, Wto, 2048, 2048);
  k_gemm<ushort_t><<<dim3(64, 24), 256, 0, stream>>>(Xb, Wtqkv, QKVt, 8192, 3072, 2048);
  k_normrope<<<40960, 256, 0, stream>>>(QKVt, cosT, sinT, qw, kw, Qr, Kr);
  k_vtrans<<<dim3(32, 2, 16), 256, 0, stream>>>(QKVt, Vt);
  k_attn<<<dim3(32, 64), 256, 0, stream>>>(Qr, Kr, Vt, AO);
  k_gemm<float><<<dim3(64, 16), 256, 0, stream>>>(AO, Wto, out, 8192, 2048, 2048);
}

// Round 3
// 619.878 us; speedup vs baseline: 1.2194x; 1.1961x over previous
//
#include <hip/hip_runtime.h>

#define DEVI __device__ __forceinline__

#define B_    4
#define S_    2048
#define HID_  2048
#define H_    16
#define KV_   4
#define D_    128
#define NQKV_ 3072
#define SCALE_ 0.08838834764831845f
#define L2E_   1.44269504088896340736f

typedef __bf16 bf16x8 __attribute__((ext_vector_type(8)));
typedef float  f32x4  __attribute__((ext_vector_type(4)));
typedef float  f32x16 __attribute__((ext_vector_type(16)));
typedef unsigned short ushort_t;

DEVI unsigned short f2bu(float f) {            // f32 -> bf16 bits, RNE
  unsigned u = __float_as_uint(f);
  u += 0x7fffu + ((u >> 16) & 1u);
  return (unsigned short)(u >> 16);
}
DEVI float bu2f(unsigned short s) { return __uint_as_float(((unsigned)s) << 16); }
DEVI unsigned pk2(float a, float b) {
  return (unsigned)f2bu(a) | ((unsigned)f2bu(b) << 16);
}

DEVI void storev(ushort_t* p, float v) { *p = f2bu(v); }
DEVI void storev(float* p, float v)    { *p = v; }

// async global->LDS, 16B/lane; LDS dest = wave-uniform base + lane*16 (m104)
DEVI void gl_lds16(const void* gptr, void* ldsptr) {
  __builtin_amdgcn_global_load_lds(
      (const __attribute__((address_space(1))) void*)gptr,
      (__attribute__((address_space(3))) void*)ldsptr, 16, 0, 0);
}

// ---------------- f32 -> bf16 elementwise (8/thread) ----------------
__global__ void k_cvt(const float* __restrict__ in, ushort_t* __restrict__ out, int n8) {
  int i = blockIdx.x * blockDim.x + threadIdx.x;
  if (i >= n8) return;
  const float4* p = (const float4*)in + (size_t)i * 2;
  float4 a = p[0], b = p[1];
  uint4 o;
  o.x = pk2(a.x, a.y);
  o.y = pk2(a.z, a.w);
  o.z = pk2(b.x, b.y);
  o.w = pk2(b.z, b.w);
  ((uint4*)out)[i] = o;
}

// ---------------- W (K x N, f32) -> Wt (N x K, bf16), LDS tile transpose ----
__global__ void k_transw(const float* __restrict__ in, ushort_t* __restrict__ out,
                         int K, int N) {
  __shared__ float tile[64][65];                       // +1 pad: conflict-free
  int k0 = blockIdx.x * 64, n0 = blockIdx.y * 64;
  int c = threadIdx.x & 63, r0 = threadIdx.x >> 6;
  #pragma unroll
  for (int i = 0; i < 16; ++i) {
    int r = r0 * 16 + i;
    tile[r][c] = in[(size_t)(k0 + r) * N + n0 + c];    // coalesced read
  }
  __syncthreads();
  #pragma unroll
  for (int i = 0; i < 16; ++i) {
    int r = r0 * 16 + i;
    out[(size_t)(n0 + r) * K + k0 + c] = f2bu(tile[c][r]);  // coalesced write
  }
}

// ---------------- V slice of QKV -> V^T (B,KV,D,S), LDS transpose ----------
__global__ void k_vtrans(const ushort_t* __restrict__ qkv, ushort_t* __restrict__ Vt) {
  __shared__ ushort_t tile[64][65];
  int s0 = blockIdx.x * 64, d0 = blockIdx.y * 64;
  int bkv = blockIdx.z, b = bkv >> 2, vh = bkv & 3;
  int c = threadIdx.x & 63, r0 = (threadIdx.x >> 6) * 16;
  const ushort_t* src = qkv + (size_t)(b * S_ + s0) * NQKV_ + 2560 + vh * 128 + d0;
  #pragma unroll
  for (int i = 0; i < 16; ++i) {
    int r = r0 + i;
    tile[r][c] = src[(size_t)r * NQKV_ + c];           // coalesced 128B rows
  }
  __syncthreads();
  ushort_t* dst = Vt + ((size_t)(b * KV_ + vh) * D_ + d0) * S_ + s0;
  #pragma unroll
  for (int i = 0; i < 16; ++i) {
    int r = r0 + i;
    dst[(size_t)r * S_ + c] = tile[c][r];              // coalesced 128B rows
  }
}

// ---------------- bf16 GEMM: C(MxN) = A(MxK) * Bt(NxK)^T, m97 structure ----
template <typename OutT>
__global__ __launch_bounds__(256)
void k_gemm(const ushort_t* __restrict__ A, const ushort_t* __restrict__ Bt,
            OutT* __restrict__ C, int M, int N, int K) {
  __shared__ __align__(16) ushort_t As[128 * 64];      // [m][k] 16KB
  __shared__ __align__(16) ushort_t Bs[128 * 64];      // [n][k] 16KB
  const int tid = threadIdx.x;
  const int wave = tid >> 6, lane = tid & 63;
  const int wr = wave >> 1, wc = wave & 1;
  const int h4 = lane >> 4, c16 = lane & 15;
  const int m0 = blockIdx.x * 128, n0 = blockIdx.y * 128;

  const int srow  = wave * 8 + (lane >> 3);
  const int scolb = (lane & 7) * 16;

  const ushort_t* Ap = A  + (size_t)m0 * K;
  const ushort_t* Bp = Bt + (size_t)n0 * K;

  f32x4 acc[4][4] = {};

  for (int kt = 0; kt < K; kt += 64) {
    __syncthreads();
    #pragma unroll
    for (int p = 0; p < 4; ++p) {
      int row = p * 32 + srow;
      gl_lds16((const char*)(Ap + (size_t)row * K + kt) + scolb,
               (char*)As + p * 4096 + wave * 1024);
      gl_lds16((const char*)(Bp + (size_t)row * K + kt) + scolb,
               (char*)Bs + p * 4096 + wave * 1024);
    }
    __syncthreads();
    #pragma unroll
    for (int kc = 0; kc < 2; ++kc) {
      bf16x8 af[4], bfr[4];
      #pragma unroll
      for (int m = 0; m < 4; ++m)
        af[m] = *(const bf16x8*)((const char*)As + (wr * 64 + m * 16 + c16) * 128 + kc * 64 + h4 * 16);
      #pragma unroll
      for (int n = 0; n < 4; ++n)
        bfr[n] = *(const bf16x8*)((const char*)Bs + (wc * 64 + n * 16 + c16) * 128 + kc * 64 + h4 * 16);
      #pragma unroll
      for (int m = 0; m < 4; ++m)
        #pragma unroll
        for (int n = 0; n < 4; ++n)
          acc[m][n] = __builtin_amdgcn_mfma_f32_16x16x32_bf16(af[m], bfr[n], acc[m][n], 0, 0, 0);
    }
  }
  #pragma unroll
  for (int m = 0; m < 4; ++m)
    #pragma unroll
    for (int n = 0; n < 4; ++n)
      #pragma unroll
      for (int r = 0; r < 4; ++r) {
        int grow = m0 + wr * 64 + m * 16 + h4 * 4 + r;
        int gcol = n0 + wc * 64 + n * 16 + c16;
        storev(&C[(size_t)grow * N + gcol], acc[m][n][r]);
      }
}

// ---------------- RMSNorm + RoPE (Q,K only) ----------------
// one wave per (b,s,row): rows 0..15 Q-heads, 16..19 K-heads
// Q additionally folds SCALE * log2(e) so attention scores are in log2 units.
__global__ void k_normrope(const ushort_t* __restrict__ qkv,
                           const float* __restrict__ cosT, const float* __restrict__ sinT,
                           const float* __restrict__ qw, const float* __restrict__ kw,
                           ushort_t* __restrict__ Qr,   // (B,H,S,D)
                           ushort_t* __restrict__ Kr) { // (B,KV,S,D)
  int wid = blockIdx.x * 4 + (threadIdx.x >> 6);
  int lane = threadIdx.x & 63;
  int sub = wid % 20;
  int bs = wid / 20;
  int b = bs >> 11, s = bs & 2047;
  bool isQ = sub < 16;
  int head = isQ ? sub : sub - 16;
  const ushort_t* rp = qkv + (size_t)bs * NQKV_ + (isQ ? head * 128 : 2048 + head * 128);
  float e0 = bu2f(rp[lane]);
  float e1 = bu2f(rp[lane + 64]);
  float ss2 = e0 * e0 + e1 * e1;
  #pragma unroll
  for (int off = 32; off; off >>= 1) ss2 += __shfl_xor(ss2, off);
  float rinv = rsqrtf(ss2 * (1.0f / 128.0f) + 1e-6f);
  const float* w = isQ ? qw : kw;
  float y0 = e0 * rinv * w[lane];
  float y1 = e1 * rinv * w[lane + 64];
  float c0 = cosT[s * 128 + lane],      sn0 = sinT[s * 128 + lane];
  float c1 = cosT[s * 128 + lane + 64], sn1 = sinT[s * 128 + lane + 64];
  float o0 = y0 * c0 - y1 * sn0;
  float o1 = y1 * c1 + y0 * sn1;
  if (isQ) { o0 *= (SCALE_ * L2E_); o1 *= (SCALE_ * L2E_); }
  ushort_t* op = isQ ? (Qr + ((size_t)(b * H_ + head) * S_ + s) * D_)
                     : (Kr + ((size_t)(b * KV_ + head) * S_ + s) * D_);
  op[lane]      = f2bu(o0);
  op[lane + 64] = f2bu(o1);
}

// ---------------- flash attention v3 ---------------------------------------
// 4 waves x 32 q-rows (QBLK=128), KVBLK=64, mfma 32x32x16 throughout.
// scores^T = K*Q^T so q = lane&31 end-to-end; P stays in registers via
// cvt-pack + v_permlane32_swap_b32 (T12); defer-max rescale (T13);
// double-buffered K/V LDS, 1 barrier/tile; setprio around MFMA (T5).
__global__ __launch_bounds__(256, 2)
void k_attn(const ushort_t* __restrict__ Qr, const ushort_t* __restrict__ Kr,
            const ushort_t* __restrict__ Vt, ushort_t* __restrict__ AO) {
  __shared__ __align__(16) ushort_t Ks[2][64 * 128];  // [kv][d] swizzled, 2x16KB
  __shared__ __align__(16) ushort_t Vs[2][128 * 64];  // [d][kv] swizzled, 2x16KB
  const int bh = blockIdx.y;
  const int b = bh >> 4, h = bh & 15, kvh = h >> 2;
  const int q0 = blockIdx.x * 128;
  const int tid = threadIdx.x;
  const int wave = tid >> 6, lane = tid & 63;
  const int l31 = lane & 31, hi = lane >> 5;

  // Q B-fragments (32x32x16): lane owns q-col = l31; elem i -> d = kc*16+hi*8+i
  const ushort_t* qp = Qr + ((size_t)(b * H_ + h) * S_ + q0 + wave * 32 + l31) * D_;
  bf16x8 qf[8];
  #pragma unroll
  for (int kc = 0; kc < 8; ++kc)
    qf[kc] = *(const bf16x8*)(qp + kc * 16 + hi * 8);

  const ushort_t* Kg = Kr + (size_t)(b * KV_ + kvh) * S_ * D_;
  const ushort_t* Vg = Vt + (size_t)(b * KV_ + kvh) * D_ * S_;

  const int soff = wave * 1024 + lane * 16;

  float mrow = -1e30f, lsum = 0.0f;
  f32x16 Of[4] = {};                                  // O^T: rows d, col q=l31

#define STAGE(bufi, s0)                                                        \
  {                                                                            \
    _Pragma("unroll")                                                          \
    for (int p = 0; p < 4; ++p) {                                              \
      int off = p * 4096 + soff;                                               \
      int krow = off >> 8, kcolb = off & 255;                                  \
      int ksc = kcolb ^ ((krow & 7) << 4);                                     \
      gl_lds16((const char*)(Kg + (size_t)((s0) + krow) * D_) + ksc,           \
               (char*)Ks[bufi] + p * 4096 + wave * 1024);                      \
      int vrow = off >> 7, vcolb = off & 127;                                  \
      int vsc = vcolb ^ ((vrow & 7) << 4);                                     \
      gl_lds16((const char*)(Vg + (size_t)vrow * S_ + (s0)) + vsc,             \
               (char*)Vs[bufi] + p * 4096 + wave * 1024);                      \
    }                                                                          \
  }

  STAGE(0, 0);
  asm volatile("s_waitcnt vmcnt(0)" ::: "memory");
  __builtin_amdgcn_s_barrier();

  for (int nt = 0; nt < S_ / 64; ++nt) {
    const int cur = nt & 1;
    if (nt + 1 < S_ / 64) STAGE(cur ^ 1, (nt + 1) * 64);

    // ---- scores^T (64kv x 32q) = K * Q^T, 2 kv-tiles x 8 k-steps
    f32x16 st[2] = {};
    __builtin_amdgcn_s_setprio(1);
    #pragma unroll
    for (int t = 0; t < 2; ++t) {
      const int row = t * 32 + l31;
      const int xr = (row & 7) << 4;
      #pragma unroll
      for (int kc = 0; kc < 8; ++kc) {
        bf16x8 kf = *(const bf16x8*)((const char*)Ks[cur] + row * 256 +
                                     ((kc * 32 + hi * 16) ^ xr));
        st[t] = __builtin_amdgcn_mfma_f32_32x32x16_bf16(kf, qf[kc], st[t], 0, 0, 0);
      }
    }
    __builtin_amdgcn_s_setprio(0);

    // ---- online softmax (scores already in log2 units)
    // lane holds q=l31; kv = t*32 + (r&3) + 8*(r>>2) + 4*hi over r=0..15
    float tmax = st[0][0];
    #pragma unroll
    for (int r = 1; r < 16; ++r) tmax = fmaxf(tmax, st[0][r]);
    #pragma unroll
    for (int r = 0; r < 16; ++r) tmax = fmaxf(tmax, st[1][r]);
    tmax = fmaxf(tmax, __shfl_xor(tmax, 32));

    if (!__all(tmax - mrow <= 8.0f)) {                // T13 defer-max, THR=8
      const float mnew = fmaxf(mrow, tmax);
      const float corr = exp2f(mrow - mnew);
      #pragma unroll
      for (int dt = 0; dt < 4; ++dt)
        #pragma unroll
        for (int r = 0; r < 16; ++r) Of[dt][r] *= corr;
      lsum *= corr;
      mrow = mnew;
    }

    float psum = 0.0f;
    unsigned u[16];                                    // packed P pairs
    #pragma unroll
    for (int t = 0; t < 2; ++t)
      #pragma unroll
      for (int j = 0; j < 8; ++j) {
        float pa = exp2f(st[t][2 * j]     - mrow);
        float pb = exp2f(st[t][2 * j + 1] - mrow);
        psum += pa + pb;
        unsigned short xa = __builtin_bit_cast(unsigned short, (__bf16)pa);
        unsigned short xb = __builtin_bit_cast(unsigned short, (__bf16)pb);
        u[t * 8 + j] = (unsigned)xa | ((unsigned)xb << 16);
      }
    lsum += psum;

    // ---- PV: O^T(d,q) += V^T(d,kv) * P^T(kv,q), 4 kv-steps x 4 d-tiles
    #pragma unroll
    for (int kt = 0; kt < 4; ++kt) {
      const int base = (kt >> 1) * 8 + (kt & 1) * 4;
      unsigned w0 = u[base], w1 = u[base + 1], w2 = u[base + 2], w3 = u[base + 3];
      // swap hi32-of-dst with lo32-of-src: yields all 4 B-frag words (T12)
      asm("v_permlane32_swap_b32 %0, %1" : "+v"(w0), "+v"(w2));
      asm("v_permlane32_swap_b32 %0, %1" : "+v"(w1), "+v"(w3));
      uint4 pw; pw.x = w0; pw.y = w1; pw.z = w2; pw.w = w3;
      bf16x8 pb = __builtin_bit_cast(bf16x8, pw);
      __builtin_amdgcn_s_setprio(1);
      #pragma unroll
      for (int dt = 0; dt < 4; ++dt) {
        const int row = dt * 32 + l31;
        bf16x8 vb = *(const bf16x8*)((const char*)Vs[cur] + row * 128 +
                                     ((kt * 32 + hi * 16) ^ ((row & 7) << 4)));
        Of[dt] = __builtin_amdgcn_mfma_f32_32x32x16_bf16(vb, pb, Of[dt], 0, 0, 0);
      }
      __builtin_amdgcn_s_setprio(0);
    }

    asm volatile("s_waitcnt vmcnt(0)" ::: "memory");
    __builtin_amdgcn_s_barrier();
  }
#undef STAGE

  lsum += __shfl_xor(lsum, 32);
  const float inv = 1.0f / lsum;

  // O^T: lane q=l31; d = dt*32 + (r&3) + 8*(r>>2) + 4*hi
  const int s = q0 + wave * 32 + l31;
  ushort_t* aop = AO + ((size_t)(b * S_ + s) * H_ + h) * D_;
  #pragma unroll
  for (int dt = 0; dt < 4; ++dt)
    #pragma unroll
    for (int g = 0; g < 4; ++g) {
      const int d0 = dt * 32 + g * 8 + hi * 4;
      const int r0 = g * 4;
      uint2 o;
      o.x = pk2(Of[dt][r0]     * inv, Of[dt][r0 + 1] * inv);
      o.y = pk2(Of[dt][r0 + 2] * inv, Of[dt][r0 + 3] * inv);
      *(uint2*)(aop + d0) = o;
    }
}

extern "C" void kernel_launch(void* const* d_in, const int* in_sizes, int n_in,
                              void* d_out, int out_size, void* d_ws, size_t ws_size,
                              hipStream_t stream) {
  const float* x    = (const float*)d_in[0];
  const float* cosT = (const float*)d_in[1];
  const float* sinT = (const float*)d_in[2];
  const float* Wq   = (const float*)d_in[3];
  const float* Wk   = (const float*)d_in[4];
  const float* Wv   = (const float*)d_in[5];
  const float* Wo   = (const float*)d_in[6];
  const float* qw   = (const float*)d_in[7];
  const float* kw   = (const float*)d_in[8];
  float* out = (float*)d_out;

  // workspace layout (121,634,816 B total, with aliasing)
  char* ws = (char*)d_ws;
  ushort_t* Xb    = (ushort_t*)(ws + 0);           // 33,554,432  X bf16 (8192x2048)
  ushort_t* QKVt  = (ushort_t*)(ws + 33554432);    // 50,331,648  QKV bf16 (8192x3072)
  ushort_t* Wtqkv = (ushort_t*)(ws + 83886080);    // 12,582,912  [Wq|Wk|Wv]^T (3072x2048)
  ushort_t* Wto   = (ushort_t*)(ws + 96468992);    //  8,388,608  Wo^T (2048x2048)
  ushort_t* Kr    = (ushort_t*)(ws + 104857600);   //  8,388,608  K (B,KV,S,D)
  ushort_t* Vt    = (ushort_t*)(ws + 113246208);   //  8,388,608  V^T (B,KV,D,S)
  ushort_t* Qr = Xb;     // alias: X dead after gemm1
  ushort_t* AO = QKVt;   // alias: QKV dead after normrope+vtrans

  k_cvt<<<8192, 256, 0, stream>>>(x, Xb, 2097152);
  k_transw<<<dim3(32, 32), 256, 0, stream>>>(Wq, Wtqkv, 2048, 2048);
  k_transw<<<dim3(32, 8),  256, 0, stream>>>(Wk, Wtqkv + (size_t)2048 * 2048, 2048, 512);
  k_transw<<<dim3(32, 8),  256, 0, stream>>>(Wv, Wtqkv + (size_t)2560 * 2048, 2048, 512);
  k_transw<<<dim3(32, 32), 256, 0, stream>>>(Wo, Wto, 2048, 2048);
  k_gemm<ushort_t><<<dim3(64, 24), 256, 0, stream>>>(Xb, Wtqkv, QKVt, 8192, 3072, 2048);
  k_normrope<<<40960, 256, 0, stream>>>(QKVt, cosT, sinT, qw, kw, Qr, Kr);
  k_vtrans<<<dim3(32, 2, 16), 256, 0, stream>>>(QKVt, Vt);
  k_attn<<<dim3(16, 64), 256, 0, stream>>>(Qr, Kr, Vt, AO);
  k_gemm<float><<<dim3(64, 16), 256, 0, stream>>>(AO, Wto, out, 8192, 2048, 2048);
}

// Round 4
// 613.134 us; speedup vs baseline: 1.2329x; 1.0110x over previous
//
#include <hip/hip_runtime.h>

#define DEVI __device__ __forceinline__

#define B_    4
#define S_    2048
#define HID_  2048
#define H_    16
#define KV_   4
#define D_    128
#define NQKV_ 3072
#define SCALE_ 0.08838834764831845f
#define L2E_   1.44269504088896340736f

typedef __bf16 bf16x8 __attribute__((ext_vector_type(8)));
typedef float  f32x4  __attribute__((ext_vector_type(4)));
typedef float  f32x16 __attribute__((ext_vector_type(16)));
typedef unsigned short ushort_t;

DEVI unsigned short f2bu(float f) {            // f32 -> bf16 bits, RNE
  unsigned u = __float_as_uint(f);
  u += 0x7fffu + ((u >> 16) & 1u);
  return (unsigned short)(u >> 16);
}
DEVI float bu2f(unsigned short s) { return __uint_as_float(((unsigned)s) << 16); }
DEVI unsigned pk2(float a, float b) {
  return (unsigned)f2bu(a) | ((unsigned)f2bu(b) << 16);
}

DEVI void storev(ushort_t* p, float v) { *p = f2bu(v); }
DEVI void storev(float* p, float v)    { *p = v; }

// async global->LDS, 16B/lane; LDS dest = wave-uniform base + lane*16 (m104)
DEVI void gl_lds16(const void* gptr, void* ldsptr) {
  __builtin_amdgcn_global_load_lds(
      (const __attribute__((address_space(1))) void*)gptr,
      (__attribute__((address_space(3))) void*)ldsptr, 16, 0, 0);
}

// ---------------- f32 -> bf16 elementwise (8/thread) ----------------
__global__ void k_cvt(const float* __restrict__ in, ushort_t* __restrict__ out, int n8) {
  int i = blockIdx.x * blockDim.x + threadIdx.x;
  if (i >= n8) return;
  const float4* p = (const float4*)in + (size_t)i * 2;
  float4 a = p[0], b = p[1];
  uint4 o;
  o.x = pk2(a.x, a.y);
  o.y = pk2(a.z, a.w);
  o.z = pk2(b.x, b.y);
  o.w = pk2(b.z, b.w);
  ((uint4*)out)[i] = o;
}

// ---------------- W (K x N, f32) -> Wt (N x K, bf16), LDS tile transpose ----
__global__ void k_transw(const float* __restrict__ in, ushort_t* __restrict__ out,
                         int K, int N) {
  __shared__ float tile[64][65];                       // +1 pad: conflict-free
  int k0 = blockIdx.x * 64, n0 = blockIdx.y * 64;
  int c = threadIdx.x & 63, r0 = threadIdx.x >> 6;
  #pragma unroll
  for (int i = 0; i < 16; ++i) {
    int r = r0 * 16 + i;
    tile[r][c] = in[(size_t)(k0 + r) * N + n0 + c];    // coalesced read
  }
  __syncthreads();
  #pragma unroll
  for (int i = 0; i < 16; ++i) {
    int r = r0 * 16 + i;
    out[(size_t)(n0 + r) * K + k0 + c] = f2bu(tile[c][r]);  // coalesced write
  }
}

// ---------------- V slice of QKV -> V^T (B,KV,D,S), LDS transpose ----------
__global__ void k_vtrans(const ushort_t* __restrict__ qkv, ushort_t* __restrict__ Vt) {
  __shared__ ushort_t tile[64][65];
  int s0 = blockIdx.x * 64, d0 = blockIdx.y * 64;
  int bkv = blockIdx.z, b = bkv >> 2, vh = bkv & 3;
  int c = threadIdx.x & 63, r0 = (threadIdx.x >> 6) * 16;
  const ushort_t* src = qkv + (size_t)(b * S_ + s0) * NQKV_ + 2560 + vh * 128 + d0;
  #pragma unroll
  for (int i = 0; i < 16; ++i) {
    int r = r0 + i;
    tile[r][c] = src[(size_t)r * NQKV_ + c];           // coalesced 128B rows
  }
  __syncthreads();
  ushort_t* dst = Vt + ((size_t)(b * KV_ + vh) * D_ + d0) * S_ + s0;
  #pragma unroll
  for (int i = 0; i < 16; ++i) {
    int r = r0 + i;
    dst[(size_t)r * S_ + c] = tile[c][r];              // coalesced 128B rows
  }
}

// ---------------- bf16 GEMM: C(MxN) = A(MxK) * Bt(NxK)^T, m97 structure ----
// T1: XCD-aware blockIdx swizzle (grid.x*grid.y % 8 == 0 at all call sites)
template <typename OutT>
__global__ __launch_bounds__(256)
void k_gemm(const ushort_t* __restrict__ A, const ushort_t* __restrict__ Bt,
            OutT* __restrict__ C, int M, int N, int K) {
  __shared__ __align__(16) ushort_t As[128 * 64];      // [m][k] 16KB
  __shared__ __align__(16) ushort_t Bs[128 * 64];      // [n][k] 16KB
  const int tid = threadIdx.x;
  const int wave = tid >> 6, lane = tid & 63;
  const int wr = wave >> 1, wc = wave & 1;
  const int h4 = lane >> 4, c16 = lane & 15;

  const int bid = blockIdx.y * gridDim.x + blockIdx.x;
  const int cpx = (gridDim.x * gridDim.y) >> 3;
  const int swz = (bid & 7) * cpx + (bid >> 3);        // m157 XCD swizzle
  const int m0 = (swz % gridDim.x) * 128, n0 = (swz / gridDim.x) * 128;

  const int srow  = wave * 8 + (lane >> 3);
  const int scolb = (lane & 7) * 16;

  const ushort_t* Ap = A  + (size_t)m0 * K;
  const ushort_t* Bp = Bt + (size_t)n0 * K;

  f32x4 acc[4][4] = {};

  for (int kt = 0; kt < K; kt += 64) {
    __syncthreads();
    #pragma unroll
    for (int p = 0; p < 4; ++p) {
      int row = p * 32 + srow;
      gl_lds16((const char*)(Ap + (size_t)row * K + kt) + scolb,
               (char*)As + p * 4096 + wave * 1024);
      gl_lds16((const char*)(Bp + (size_t)row * K + kt) + scolb,
               (char*)Bs + p * 4096 + wave * 1024);
    }
    __syncthreads();
    #pragma unroll
    for (int kc = 0; kc < 2; ++kc) {
      bf16x8 af[4], bfr[4];
      #pragma unroll
      for (int m = 0; m < 4; ++m)
        af[m] = *(const bf16x8*)((const char*)As + (wr * 64 + m * 16 + c16) * 128 + kc * 64 + h4 * 16);
      #pragma unroll
      for (int n = 0; n < 4; ++n)
        bfr[n] = *(const bf16x8*)((const char*)Bs + (wc * 64 + n * 16 + c16) * 128 + kc * 64 + h4 * 16);
      #pragma unroll
      for (int m = 0; m < 4; ++m)
        #pragma unroll
        for (int n = 0; n < 4; ++n)
          acc[m][n] = __builtin_amdgcn_mfma_f32_16x16x32_bf16(af[m], bfr[n], acc[m][n], 0, 0, 0);
    }
  }
  #pragma unroll
  for (int m = 0; m < 4; ++m)
    #pragma unroll
    for (int n = 0; n < 4; ++n)
      #pragma unroll
      for (int r = 0; r < 4; ++r) {
        int grow = m0 + wr * 64 + m * 16 + h4 * 4 + r;
        int gcol = n0 + wc * 64 + n * 16 + c16;
        storev(&C[(size_t)grow * N + gcol], acc[m][n][r]);
      }
}

// ---------------- RMSNorm + RoPE (Q,K only) ----------------
// one wave per (b,s,row): rows 0..15 Q-heads, 16..19 K-heads
// Q additionally folds SCALE * log2(e) so attention scores are in log2 units.
__global__ void k_normrope(const ushort_t* __restrict__ qkv,
                           const float* __restrict__ cosT, const float* __restrict__ sinT,
                           const float* __restrict__ qw, const float* __restrict__ kw,
                           ushort_t* __restrict__ Qr,   // (B,H,S,D)
                           ushort_t* __restrict__ Kr) { // (B,KV,S,D)
  int wid = blockIdx.x * 4 + (threadIdx.x >> 6);
  int lane = threadIdx.x & 63;
  int sub = wid % 20;
  int bs = wid / 20;
  int b = bs >> 11, s = bs & 2047;
  bool isQ = sub < 16;
  int head = isQ ? sub : sub - 16;
  const ushort_t* rp = qkv + (size_t)bs * NQKV_ + (isQ ? head * 128 : 2048 + head * 128);
  float e0 = bu2f(rp[lane]);
  float e1 = bu2f(rp[lane + 64]);
  float ss2 = e0 * e0 + e1 * e1;
  #pragma unroll
  for (int off = 32; off; off >>= 1) ss2 += __shfl_xor(ss2, off);
  float rinv = rsqrtf(ss2 * (1.0f / 128.0f) + 1e-6f);
  const float* w = isQ ? qw : kw;
  float y0 = e0 * rinv * w[lane];
  float y1 = e1 * rinv * w[lane + 64];
  float c0 = cosT[s * 128 + lane],      sn0 = sinT[s * 128 + lane];
  float c1 = cosT[s * 128 + lane + 64], sn1 = sinT[s * 128 + lane + 64];
  float o0 = y0 * c0 - y1 * sn0;
  float o1 = y1 * c1 + y0 * sn1;
  if (isQ) { o0 *= (SCALE_ * L2E_); o1 *= (SCALE_ * L2E_); }
  ushort_t* op = isQ ? (Qr + ((size_t)(b * H_ + head) * S_ + s) * D_)
                     : (Kr + ((size_t)(b * KV_ + head) * S_ + s) * D_);
  op[lane]      = f2bu(o0);
  op[lane + 64] = f2bu(o1);
}

// ---------------- flash attention v4 ---------------------------------------
// 4 waves x 32 q-rows (QBLK=128), KVBLK=64, mfma 32x32x16 throughout.
// scores^T = K*Q^T so q = lane&31 end-to-end; in-register P via cvt-pack +
// v_permlane32_swap_b32 (T12); defer-max (T13); setprio (T5).
// SINGLE 32KB K/V buffer: occupancy ~4 blocks/CU; cross-block overlap hides
// the stage stall (m114/m97 pattern), and LDS read addrs are loop-invariant.
__global__ __launch_bounds__(256)
void k_attn(const ushort_t* __restrict__ Qr, const ushort_t* __restrict__ Kr,
            const ushort_t* __restrict__ Vt, ushort_t* __restrict__ AO) {
  __shared__ __align__(16) ushort_t Ks[64 * 128];     // [kv][d] swizzled, 16KB
  __shared__ __align__(16) ushort_t Vs[128 * 64];     // [d][kv] swizzled, 16KB

  const int bid0 = blockIdx.y * gridDim.x + blockIdx.x;     // 1024 blocks
  const int swzb = (bid0 & 7) * 128 + (bid0 >> 3);          // T1 XCD swizzle
  const int bh = swzb >> 4;
  const int b = bh >> 4, h = bh & 15, kvh = h >> 2;
  const int q0 = (swzb & 15) * 128;

  const int tid = threadIdx.x;
  const int wave = tid >> 6, lane = tid & 63;
  const int l31 = lane & 31, hi = lane >> 5;

  // Q B-fragments (32x32x16): lane owns q-col = l31; elem i -> d = kc*16+hi*8+i
  const ushort_t* qp = Qr + ((size_t)(b * H_ + h) * S_ + q0 + wave * 32 + l31) * D_;
  bf16x8 qf[8];
  #pragma unroll
  for (int kc = 0; kc < 8; ++kc)
    qf[kc] = *(const bf16x8*)(qp + kc * 16 + hi * 8);

  const ushort_t* Kg = Kr + (size_t)(b * KV_ + kvh) * S_ * D_;
  const ushort_t* Vg = Vt + (size_t)(b * KV_ + kvh) * D_ * S_;

  const int soff = wave * 1024 + lane * 16;

  float mrow = -1e30f, lsum = 0.0f;
  f32x16 Of[4] = {};                                  // O^T: rows d, col q=l31

  for (int nt = 0; nt < S_ / 64; ++nt) {
    const int s0 = nt * 64;
    // ---- stage K/V tile (pre-swizzled global src, linear LDS dest)
    #pragma unroll
    for (int p = 0; p < 4; ++p) {
      int off = p * 4096 + soff;
      int krow = off >> 8, kcolb = off & 255;
      int ksc = kcolb ^ ((krow & 7) << 4);
      gl_lds16((const char*)(Kg + (size_t)(s0 + krow) * D_) + ksc,
               (char*)Ks + p * 4096 + wave * 1024);
      int vrow = off >> 7, vcolb = off & 127;
      int vsc = vcolb ^ ((vrow & 7) << 4);
      gl_lds16((const char*)(Vg + (size_t)vrow * S_ + s0) + vsc,
               (char*)Vs + p * 4096 + wave * 1024);
    }
    __syncthreads();                                  // vmcnt(0) drain + barrier

    // ---- scores^T (64kv x 32q) = K * Q^T, 2 kv-tiles x 8 k-steps
    f32x16 st[2] = {};
    __builtin_amdgcn_s_setprio(1);
    #pragma unroll
    for (int t = 0; t < 2; ++t) {
      const int row = t * 32 + l31;
      const int xr = (row & 7) << 4;
      #pragma unroll
      for (int kc = 0; kc < 8; ++kc) {
        bf16x8 kf = *(const bf16x8*)((const char*)Ks + row * 256 +
                                     ((kc * 32 + hi * 16) ^ xr));
        st[t] = __builtin_amdgcn_mfma_f32_32x32x16_bf16(kf, qf[kc], st[t], 0, 0, 0);
      }
    }
    __builtin_amdgcn_s_setprio(0);

    // ---- online softmax (scores already in log2 units)
    float tmax = st[0][0];
    #pragma unroll
    for (int r = 1; r < 16; ++r) tmax = fmaxf(tmax, st[0][r]);
    #pragma unroll
    for (int r = 0; r < 16; ++r) tmax = fmaxf(tmax, st[1][r]);
    tmax = fmaxf(tmax, __shfl_xor(tmax, 32));

    if (!__all(tmax - mrow <= 8.0f)) {                // T13 defer-max, THR=8
      const float mnew = fmaxf(mrow, tmax);
      const float corr = exp2f(mrow - mnew);
      #pragma unroll
      for (int dt = 0; dt < 4; ++dt)
        #pragma unroll
        for (int r = 0; r < 16; ++r) Of[dt][r] *= corr;
      lsum *= corr;
      mrow = mnew;
    }

    float psum = 0.0f;
    unsigned u[16];                                    // packed P pairs
    #pragma unroll
    for (int t = 0; t < 2; ++t)
      #pragma unroll
      for (int j = 0; j < 8; ++j) {
        float pa = exp2f(st[t][2 * j]     - mrow);
        float pb = exp2f(st[t][2 * j + 1] - mrow);
        psum += pa + pb;
        unsigned short xa = __builtin_bit_cast(unsigned short, (__bf16)pa);
        unsigned short xb = __builtin_bit_cast(unsigned short, (__bf16)pb);
        u[t * 8 + j] = (unsigned)xa | ((unsigned)xb << 16);
      }
    lsum += psum;

    // ---- PV: O^T(d,q) += V^T(d,kv) * P^T(kv,q), 4 kv-steps x 4 d-tiles
    #pragma unroll
    for (int kt = 0; kt < 4; ++kt) {
      const int base = (kt >> 1) * 8 + (kt & 1) * 4;
      unsigned w0 = u[base], w1 = u[base + 1], w2 = u[base + 2], w3 = u[base + 3];
      asm("v_permlane32_swap_b32 %0, %1" : "+v"(w0), "+v"(w2));
      asm("v_permlane32_swap_b32 %0, %1" : "+v"(w1), "+v"(w3));
      uint4 pw; pw.x = w0; pw.y = w1; pw.z = w2; pw.w = w3;
      bf16x8 pb = __builtin_bit_cast(bf16x8, pw);
      __builtin_amdgcn_s_setprio(1);
      #pragma unroll
      for (int dt = 0; dt < 4; ++dt) {
        const int row = dt * 32 + l31;
        bf16x8 vb = *(const bf16x8*)((const char*)Vs + row * 128 +
                                     ((kt * 32 + hi * 16) ^ ((row & 7) << 4)));
        Of[dt] = __builtin_amdgcn_mfma_f32_32x32x16_bf16(vb, pb, Of[dt], 0, 0, 0);
      }
      __builtin_amdgcn_s_setprio(0);
    }

    __builtin_amdgcn_s_barrier();                     // compute done before restage
  }

  lsum += __shfl_xor(lsum, 32);
  const float inv = 1.0f / lsum;

  // O^T: lane q=l31; d = dt*32 + (r&3) + 8*(r>>2) + 4*hi
  const int s = q0 + wave * 32 + l31;
  ushort_t* aop = AO + ((size_t)(b * S_ + s) * H_ + h) * D_;
  #pragma unroll
  for (int dt = 0; dt < 4; ++dt)
    #pragma unroll
    for (int g = 0; g < 4; ++g) {
      const int d0 = dt * 32 + g * 8 + hi * 4;
      const int r0 = g * 4;
      uint2 o;
      o.x = pk2(Of[dt][r0]     * inv, Of[dt][r0 + 1] * inv);
      o.y = pk2(Of[dt][r0 + 2] * inv, Of[dt][r0 + 3] * inv);
      *(uint2*)(aop + d0) = o;
    }
}

extern "C" void kernel_launch(void* const* d_in, const int* in_sizes, int n_in,
                              void* d_out, int out_size, void* d_ws, size_t ws_size,
                              hipStream_t stream) {
  const float* x    = (const float*)d_in[0];
  const float* cosT = (const float*)d_in[1];
  const float* sinT = (const float*)d_in[2];
  const float* Wq   = (const float*)d_in[3];
  const float* Wk   = (const float*)d_in[4];
  const float* Wv   = (const float*)d_in[5];
  const float* Wo   = (const float*)d_in[6];
  const float* qw   = (const float*)d_in[7];
  const float* kw   = (const float*)d_in[8];
  float* out = (float*)d_out;

  // workspace layout (121,634,816 B total, with aliasing)
  char* ws = (char*)d_ws;
  ushort_t* Xb    = (ushort_t*)(ws + 0);           // 33,554,432  X bf16 (8192x2048)
  ushort_t* QKVt  = (ushort_t*)(ws + 33554432);    // 50,331,648  QKV bf16 (8192x3072)
  ushort_t* Wtqkv = (ushort_t*)(ws + 83886080);    // 12,582,912  [Wq|Wk|Wv]^T (3072x2048)
  ushort_t* Wto   = (ushort_t*)(ws + 96468992);    //  8,388,608  Wo^T (2048x2048)
  ushort_t* Kr    = (ushort_t*)(ws + 104857600);   //  8,388,608  K (B,KV,S,D)
  ushort_t* Vt    = (ushort_t*)(ws + 113246208);   //  8,388,608  V^T (B,KV,D,S)
  ushort_t* Qr = Xb;     // alias: X dead after gemm1
  ushort_t* AO = QKVt;   // alias: QKV dead after normrope+vtrans

  k_cvt<<<8192, 256, 0, stream>>>(x, Xb, 2097152);
  k_transw<<<dim3(32, 32), 256, 0, stream>>>(Wq, Wtqkv, 2048, 2048);
  k_transw<<<dim3(32, 8),  256, 0, stream>>>(Wk, Wtqkv + (size_t)2048 * 2048, 2048, 512);
  k_transw<<<dim3(32, 8),  256, 0, stream>>>(Wv, Wtqkv + (size_t)2560 * 2048, 2048, 512);
  k_transw<<<dim3(32, 32), 256, 0, stream>>>(Wo, Wto, 2048, 2048);
  k_gemm<ushort_t><<<dim3(64, 24), 256, 0, stream>>>(Xb, Wtqkv, QKVt, 8192, 3072, 2048);
  k_normrope<<<40960, 256, 0, stream>>>(QKVt, cosT, sinT, qw, kw, Qr, Kr);
  k_vtrans<<<dim3(32, 2, 16), 256, 0, stream>>>(QKVt, Vt);
  k_attn<<<dim3(16, 64), 256, 0, stream>>>(Qr, Kr, Vt, AO);
  k_gemm<float><<<dim3(64, 16), 256, 0, stream>>>(AO, Wto, out, 8192, 2048, 2048);
}